// Round 5
// baseline (733.658 us; speedup 1.0000x reference)
//
#include <hip/hip_runtime.h>
#include <hip/hip_bf16.h>
#include <stdint.h>

#define M_DIM 8192
#define N_DIM 16384
#define K_DIM 4096

typedef short short8 __attribute__((ext_vector_type(8)));
typedef float floatx4 __attribute__((ext_vector_type(4)));
typedef int i32x4 __attribute__((ext_vector_type(4)));

__device__ __forceinline__ unsigned short f2bf(float f) {
    union { float f; unsigned u; } a;
    a.f = f;
    unsigned r = a.u + 0x7FFFu + ((a.u >> 16) & 1u);
    return (unsigned short)(r >> 16);
}

#define GLDS16(g, l)                                                     \
    __builtin_amdgcn_global_load_lds(                                    \
        (const __attribute__((address_space(1))) void*)(g),              \
        (__attribute__((address_space(3))) void*)(l), 16, 0, 0)

#define SBAR() asm volatile("s_barrier" ::: "memory")
#define WAIT_LGKM0() asm volatile("s_waitcnt lgkmcnt(0)" ::: "memory")
#define WAIT_LGKM4() asm volatile("s_waitcnt lgkmcnt(4)" ::: "memory")
#define WAIT_LGKM8() asm volatile("s_waitcnt lgkmcnt(8)" ::: "memory")
#define WAIT_VM6() asm volatile("s_waitcnt vmcnt(6)" ::: "memory")
#define WAIT_VM0() asm volatile("s_waitcnt vmcnt(0)" ::: "memory")
#define SCHEDB() __builtin_amdgcn_sched_barrier(0)

// ---------------- x: per-row int8 quant (scale sx[row] = absmax/127) ----------
__global__ __launch_bounds__(256)
void quant_x_kernel(const float4* __restrict__ x, int* __restrict__ xq,
                    float* __restrict__ sx) {
    const int row = blockIdx.x;
    const int t = threadIdx.x;
    const float4* px = x + (size_t)row * (K_DIM / 4);
    float4 v[4];
    float am = 0.f;
#pragma unroll
    for (int j = 0; j < 4; ++j) {
        v[j] = px[t + j * 256];
        am = fmaxf(am, fmaxf(fmaxf(fabsf(v[j].x), fabsf(v[j].y)),
                             fmaxf(fabsf(v[j].z), fabsf(v[j].w))));
    }
#pragma unroll
    for (int m = 32; m; m >>= 1) am = fmaxf(am, __shfl_xor(am, m));
    __shared__ float red[4];
    if ((t & 63) == 0) red[t >> 6] = am;
    __syncthreads();
    am = fmaxf(fmaxf(red[0], red[1]), fmaxf(red[2], red[3]));
    const float inv = am > 0.f ? 127.f / am : 0.f;
    if (t == 0) sx[row] = am * (1.f / 127.f);
    int* xo = xq + (size_t)row * (K_DIM / 4);
#pragma unroll
    for (int j = 0; j < 4; ++j) {
        int q0 = (int)rintf(v[j].x * inv);
        int q1 = (int)rintf(v[j].y * inv);
        int q2 = (int)rintf(v[j].z * inv);
        int q3 = (int)rintf(v[j].w * inv);
        xo[t + j * 256] = (q0 & 255) | ((q1 & 255) << 8) |
                          ((q2 & 255) << 16) | ((q3 & 255) << 24);
    }
}

// ---------------- w: int32 -> int8 (q - zp), exact ----------------
__global__ void cvt_w8_kernel(const int4* __restrict__ w, int4* __restrict__ out,
                              const int* __restrict__ zp_p, int n16) {
    const int zp = *zp_p;
    int idx = blockIdx.x * blockDim.x + threadIdx.x;
    int stride = gridDim.x * blockDim.x;
    for (int i = idx; i < n16; i += stride) {
        int4 r;
        int* rp = (int*)&r;
#pragma unroll
        for (int j = 0; j < 4; ++j) {
            int4 q = w[i * 4 + j];
            rp[j] = ((q.x - zp) & 255) | (((q.y - zp) & 255) << 8) |
                    (((q.z - zp) & 255) << 16) | (((q.w - zp) & 255) << 24);
        }
        out[i] = r;
    }
}

// ================= 256x256 8-phase int8 GEMM (BK=128, 2 K-tiles/iter) =========
// Same LDS layout/swizzle/staging as R4 (verified). New: within-body ds_read
// PREFETCH — each phase issues the NEXT phase's fragment reads and waits a
// counted lgkmcnt for the current phase's data, hiding LDS latency under MFMA.
// Two A-fragment register sets (aFa/aFb) since both halves are live at once.

#define LOAD_AR(BUF, MH, AF)                                               \
    do {                                                                   \
        const char* p_ = smem + (BUF)*65536 + (MH)*16384 + wm*8192;        \
        _Pragma("unroll") for (int mf = 0; mf < 4; ++mf) {                 \
            AF[mf][0] = *(const i32x4*)(p_ + mf*2048 + laneK0);            \
            AF[mf][1] = *(const i32x4*)(p_ + mf*2048 + laneK1);            \
        }                                                                  \
    } while (0)

#define LOAD_BR(BUF, NH, BF)                                               \
    do {                                                                   \
        const char* p_ = smem + (BUF)*65536 + 32768 + (NH)*16384 + wn*4096;\
        _Pragma("unroll") for (int nf = 0; nf < 2; ++nf) {                 \
            BF[nf][0] = *(const i32x4*)(p_ + nf*2048 + laneK0);            \
            BF[nf][1] = *(const i32x4*)(p_ + nf*2048 + laneK1);            \
        }                                                                  \
    } while (0)

// self-incrementing stage pointers: each unit advances one K-tile (128 bytes)
#define STAGE_A0(BUF)                                                      \
    do {                                                                   \
        GLDS16(pA00, smem + (BUF)*65536 + st16); pA00 += 128;              \
        GLDS16(pA01, smem + (BUF)*65536 + 8192 + st16); pA01 += 128;       \
    } while (0)
#define STAGE_A1(BUF)                                                      \
    do {                                                                   \
        GLDS16(pA10, smem + (BUF)*65536 + 16384 + st16); pA10 += 128;      \
        GLDS16(pA11, smem + (BUF)*65536 + 16384 + 8192 + st16); pA11 += 128;\
    } while (0)
#define STAGE_B0(BUF)                                                      \
    do {                                                                   \
        GLDS16(pB00, smem + (BUF)*65536 + 32768 + st16); pB00 += 128;      \
        GLDS16(pB01, smem + (BUF)*65536 + 32768 + 8192 + st16); pB01 += 128;\
    } while (0)
#define STAGE_B1(BUF)                                                      \
    do {                                                                   \
        GLDS16(pB10, smem + (BUF)*65536 + 49152 + st16); pB10 += 128;      \
        GLDS16(pB11, smem + (BUF)*65536 + 49152 + 8192 + st16); pB11 += 128;\
    } while (0)

#define MFMA_Q(AF, BF, MH, NH)                                             \
    do {                                                                   \
        __builtin_amdgcn_s_setprio(1);                                     \
        _Pragma("unroll") for (int kk = 0; kk < 2; ++kk)                   \
        _Pragma("unroll") for (int mf = 0; mf < 4; ++mf)                   \
        _Pragma("unroll") for (int nf = 0; nf < 2; ++nf)                   \
            acc[(MH)*4+mf][(NH)*2+nf] =                                    \
                __builtin_amdgcn_mfma_i32_16x16x64_i8(                     \
                    AF[mf][kk], BF[nf][kk], acc[(MH)*4+mf][(NH)*2+nf],     \
                    0, 0, 0);                                              \
        __builtin_amdgcn_s_setprio(0);                                     \
    } while (0)

// WAR-safety (audited): every STAGE into region R is preceded by all waves'
// reads of R completing (counted lgkm wait) + a post-MFMA s_barrier:
//  ph2 STAGE_A0 <- aFa done at ph1 LGKM4 + SBAR
//  ph3 STAGE_B1 <- bF1 done at ph2 LGKM8 (bF1 oldest) + SBAR
//  ph4 STAGE_A1 <- aFb done at ph3 LGKM0 + SBAR
#define BODY(B, NB, SMODE)                                                 \
    do {                                                                   \
        /* phase 1: Q(0,0); reads aFa+bF0 (+prefetch bF1) */               \
        LOAD_AR(B, 0, aFa);                                                \
        LOAD_BR(B, 0, bF0);                                                \
        LOAD_BR(B, 1, bF1);                                                \
        if ((SMODE) >= 1) STAGE_B0(NB);                                    \
        SBAR(); WAIT_LGKM4();                                              \
        MFMA_Q(aFa, bF0, 0, 0);                                            \
        SBAR();                                                            \
        /* phase 2: Q(0,1); prefetch aFb */                                \
        LOAD_AR(B, 1, aFb);                                                \
        if ((SMODE) >= 2) STAGE_A0(B);                                     \
        SBAR(); WAIT_LGKM8();                                              \
        MFMA_Q(aFa, bF1, 0, 1);                                            \
        SBAR();                                                            \
        /* phase 3: Q(1,1); no reads */                                    \
        if ((SMODE) >= 2) STAGE_B1(B);                                     \
        SBAR(); WAIT_LGKM0();                                              \
        MFMA_Q(aFb, bF1, 1, 1);                                            \
        SBAR();                                                            \
        /* phase 4: Q(1,0); all operands in regs */                        \
        if ((SMODE) >= 2) STAGE_A1(B);                                     \
        SCHEDB();                                                          \
        MFMA_Q(aFb, bF0, 1, 0);                                            \
        SCHEDB();                                                          \
        if ((SMODE) == 2) { WAIT_VM6(); } else { WAIT_VM0(); }             \
        SBAR();                                                            \
    } while (0)

__global__ __launch_bounds__(512, 2)
void gemm8i_kernel(const int8_t* __restrict__ Aq, const int8_t* __restrict__ Bq,
                   const float* __restrict__ bias,
                   const float* __restrict__ scale_p,
                   const float* __restrict__ sx,
                   float* __restrict__ out) {
    __shared__ __align__(16) char smem[131072];

    const int t = threadIdx.x;
    const int lane = t & 63;
    const int wid = t >> 6;
    const int wm = wid >> 2;  // 0..1
    const int wn = wid & 3;   // 0..3

    // XCD-aware bijective swizzle (nwg=2048 divisible by 8)
    int bid = blockIdx.x;
    int sz = (bid & 7) * 256 + (bid >> 3);
    const int bx = sz & 63;
    const int by = sz >> 6;
    const int brow = by << 8;
    const int bcol = bx << 8;

    // swizzled ds_read lane offsets (128B rows, 16B slots)
    const int laneK0 = (lane & 15) * 128 + (((lane >> 4) * 16) ^ ((lane & 7) << 4));
    const int laneK1 = (lane & 15) * 128 + ((((lane >> 4) * 16) + 64) ^ ((lane & 7) << 4));

    // staging source offsets (inverse-swizzled); 1 byte per element
    size_t aoffs[2], boffs[2];
#pragma unroll
    for (int g = 0; g < 2; ++g) {
        unsigned u = g * 8192 + t * 16;
        unsigned up = u ^ (((u >> 7) & 7) << 4);
        aoffs[g] = (size_t)(brow + ((up >> 13) & 1) * 128 + ((up >> 7) & 63)) * K_DIM
                   + (up & 127);
        boffs[g] = (size_t)(bcol + ((up >> 12) & 3) * 64 + ((up >> 7) & 31)) * K_DIM
                   + (up & 127);
    }
    const int8_t* pA00 = Aq + aoffs[0];
    const int8_t* pA01 = Aq + aoffs[1];
    const int8_t* pA10 = Aq + aoffs[0] + 262144;   // +64 rows
    const int8_t* pA11 = Aq + aoffs[1] + 262144;
    const int8_t* pB00 = Bq + boffs[0];
    const int8_t* pB01 = Bq + boffs[1];
    const int8_t* pB10 = Bq + boffs[0] + 131072;   // +32 cols
    const int8_t* pB11 = Bq + boffs[1] + 131072;
    const int st16 = t * 16;

    i32x4 acc[8][4] = {};
    i32x4 aFa[4][2], aFb[4][2], bF0[2][2], bF1[2][2];

    const int NT = K_DIM / 128;  // 32

    // ---- prologue: tile0 complete + 3 units of tile1 (B0(1) staged at kt=0 ph1)
    STAGE_A0(0);
    STAGE_B0(0);
    STAGE_B1(0);
    STAGE_A1(0);
    STAGE_A0(1);
    STAGE_B1(1);
    STAGE_A1(1);
    WAIT_VM6();
    SBAR();

    // ---- main loop: 15 iters x 2 K-tiles, branchless
    for (int it = 0; it < (NT - 2) / 2; ++it) {
        BODY(0, 1, 2);
        BODY(1, 0, 2);
    }
    // ---- tail
    BODY(0, 1, 1);
    BODY(1, 0, 0);

    // ---- epilogue: out = acc * (scale*sx[row]) + bias[col]
    const float scale = *scale_p;
    const int crow0 = brow + wm * 128 + ((lane >> 4) << 2);
    const int ccol0 = bcol + wn * 64 + (lane & 15);
    float bv[4];
#pragma unroll
    for (int nf = 0; nf < 4; ++nf) bv[nf] = bias[ccol0 + nf * 16];
#pragma unroll
    for (int mf = 0; mf < 8; ++mf) {
#pragma unroll
        for (int j = 0; j < 4; ++j) {
            const int r = crow0 + mf * 16 + j;
            const float s2 = scale * sx[r];
            float* orow = out + (size_t)r * N_DIM;
#pragma unroll
            for (int nf = 0; nf < 4; ++nf)
                orow[ccol0 + nf * 16] = (float)acc[mf][nf][j] * s2 + bv[nf];
        }
    }
}

// ---------------- fallback (ws too small): fused dequant 128^2 bf16 GEMM ------
__global__ __launch_bounds__(256)
void gemm_fb_kernel(const float* __restrict__ Xf, const int* __restrict__ Wq,
                    const float* __restrict__ bias,
                    const float* __restrict__ scale_p,
                    const int* __restrict__ zp_p,
                    float* __restrict__ out) {
    const int NB = N_DIM / 128;
    int nwg = gridDim.x;
    int cpx = nwg >> 3;
    int bid = blockIdx.x;
    int swz = (bid & 7) * cpx + (bid >> 3);
    int bx = swz % NB;
    int by = swz / NB;
    const int brow = by * 128;
    const int bcol = bx * 128;

    __shared__ __align__(16) ushort sA[128 * 32];
    __shared__ __align__(16) ushort sB[128 * 32];

    const int t = threadIdx.x;
    const int lane = t & 63;
    const int wid = t >> 6;
    const int wr = wid >> 1;
    const int wc = wid & 1;

    floatx4 acc[4][4] = {};

    const int xr = t >> 1;
    const int xc = (t & 1) << 4;
    const int zp = *zp_p;

    const int arow = wr * 64 + (lane & 15);
    const int acol = (lane >> 4) << 3;
    const int brow_f = wc * 64 + (lane & 15);

    for (int k0 = 0; k0 < K_DIM; k0 += 32) {
        __syncthreads();
        const float* gx = Xf + (size_t)(brow + xr) * K_DIM + k0 + xc;
        ushort* dA = &sA[xr * 32 + xc];
#pragma unroll
        for (int i = 0; i < 4; ++i) {
            float4 v = ((const float4*)gx)[i];
            ushort4 u;
            u.x = f2bf(v.x); u.y = f2bf(v.y); u.z = f2bf(v.z); u.w = f2bf(v.w);
            *(ushort4*)(dA + i * 4) = u;
        }
        const int* gw = Wq + (size_t)(bcol + xr) * K_DIM + k0 + xc;
        ushort* dB = &sB[xr * 32 + xc];
#pragma unroll
        for (int i = 0; i < 4; ++i) {
            int4 q = ((const int4*)gw)[i];
            ushort4 u;
            u.x = f2bf((float)(q.x - zp));
            u.y = f2bf((float)(q.y - zp));
            u.z = f2bf((float)(q.z - zp));
            u.w = f2bf((float)(q.w - zp));
            *(ushort4*)(dB + i * 4) = u;
        }
        __syncthreads();

        short8 af[4], bfr[4];
#pragma unroll
        for (int m = 0; m < 4; ++m)
            af[m] = *(const short8*)&sA[(arow + m * 16) * 32 + acol];
#pragma unroll
        for (int n = 0; n < 4; ++n)
            bfr[n] = *(const short8*)&sB[(brow_f + n * 16) * 32 + acol];

#pragma unroll
        for (int m = 0; m < 4; ++m)
#pragma unroll
            for (int n = 0; n < 4; ++n)
                acc[m][n] = __builtin_amdgcn_mfma_f32_16x16x32_bf16(
                    af[m], bfr[n], acc[m][n], 0, 0, 0);
    }

    const float scale = *scale_p;
    const int colbase = bcol + wc * 64 + (lane & 15);
    const int rowbase = brow + wr * 64 + ((lane >> 4) << 2);
    float bv[4];
#pragma unroll
    for (int n = 0; n < 4; ++n) bv[n] = bias[colbase + n * 16];
#pragma unroll
    for (int m = 0; m < 4; ++m) {
        const int r0 = rowbase + m * 16;
#pragma unroll
        for (int j = 0; j < 4; ++j) {
            float* orow = out + (size_t)(r0 + j) * N_DIM;
#pragma unroll
            for (int n = 0; n < 4; ++n)
                orow[colbase + n * 16] = acc[m][n][j] * scale + bv[n];
        }
    }
}

extern "C" void kernel_launch(void* const* d_in, const int* in_sizes, int n_in,
                              void* d_out, int out_size, void* d_ws, size_t ws_size,
                              hipStream_t stream) {
    const float* x = (const float*)d_in[0];
    const int* wq = (const int*)d_in[1];
    const float* bias = (const float*)d_in[2];
    const float* scale = (const float*)d_in[3];
    const int* zp = (const int*)d_in[4];
    float* out = (float*)d_out;

    const size_t xq_bytes = (size_t)M_DIM * K_DIM;       // 32 MiB
    const size_t wb_bytes = (size_t)N_DIM * K_DIM;       // 64 MiB
    const size_t sx_bytes = (size_t)M_DIM * 4;           // 32 KiB

    if (ws_size >= xq_bytes + wb_bytes + sx_bytes) {
        int8_t* xq = (int8_t*)d_ws;
        int8_t* wb = (int8_t*)d_ws + xq_bytes;
        float* sx = (float*)((char*)d_ws + xq_bytes + wb_bytes);
        quant_x_kernel<<<M_DIM, 256, 0, stream>>>((const float4*)x, (int*)xq, sx);
        cvt_w8_kernel<<<2048, 256, 0, stream>>>((const int4*)wq, (int4*)wb, zp,
                                                (N_DIM * K_DIM) / 16);
        const int nblocks = (M_DIM / 256) * (N_DIM / 256);  // 2048
        gemm8i_kernel<<<nblocks, 512, 0, stream>>>(xq, wb, bias, scale, sx, out);
    } else {
        const int nblocks = (M_DIM / 128) * (N_DIM / 128);
        gemm_fb_kernel<<<nblocks, 256, 0, stream>>>(x, wq, bias, scale, zp, out);
    }
}